// Round 20
// baseline (77.772 us; speedup 1.0000x reference)
//
#include <hip/hip_runtime.h>
#include <math.h>

#define NROWS 4096
#define DDIM  64
#define NBINS 2048
#define NSHARD 8
#define HIST_W    0.25f    // 2048 bins over [0, 512)
#define HIST_INVW 4.0f

// ws layout (bytes):
// [0      .. 65536  )  hist8[8][2048] u32        -- zeroed by prep each call
// [65536  .. 81920  )  x_sq (4096 f32)
// [81920  .. 98304  )  y_sq (4096 f32)
// [131072 .. 2228224)  Xh, Xl, Yh, Yl (each 4096x64 bf16 = 512 KB)
//
// Fragment-major bf16 layout: (row,k) -> ((row>>4)*8 + (k>>3))*128 + (row&15)*8 + (k&7)
// => one MFMA fragment (16 rows x 32 k) = base + lane*8 shorts (coalesced 1 KB wave load).
//
// HW lessons carried:
//  - R4/R10: wave stores must cover full 128B lines; partial lines amplify ~2x.
//  - R12: prior-launch data is coherent across the kernel boundary -> plain loads.
//  - R14/R15/R16: stores need parallelism AND pipelining (2 blocks/CU x 2 tiles).
//  - R17/R18/R19: four nulls (vmcnt order, NT-vs-plain, prep staging, signaling).
//  - R20 experiment: the untested variable is STORE RUN LENGTH. 256B runs at
//    16KB stride vs harness fills' sequential stream (6.3 TB/s). New wave tile
//    16x256 -> 1KB-contiguous runs per store instruction (4x run length).

typedef __attribute__((ext_vector_type(8))) short short8;
typedef __attribute__((ext_vector_type(4))) float f32x4;

__device__ inline unsigned short f2bf(float f) {           // RNE f32 -> bf16 bits
    unsigned u = __builtin_bit_cast(unsigned, f);
    u += 0x7FFFu + ((u >> 16) & 1u);
    return (unsigned short)(u >> 16);
}
__device__ inline float bf2f(unsigned short h) {
    unsigned u = ((unsigned)h) << 16;
    return __builtin_bit_cast(float, u);
}

__global__ void prep_kernel(const float* __restrict__ X, const float* __restrict__ Y,
                            unsigned short* __restrict__ Xh, unsigned short* __restrict__ Xl,
                            unsigned short* __restrict__ Yh, unsigned short* __restrict__ Yl,
                            float* __restrict__ x_sq, float* __restrict__ y_sq,
                            unsigned* __restrict__ hist8) {
    int gid = blockIdx.x * blockDim.x + threadIdx.x;       // 0..65535
    if (gid < NSHARD * NBINS) hist8[gid] = 0u;
    int row = gid >> 3, kb = gid & 7;                      // one row-octet per thread
    int r = (row < NROWS) ? row : row - NROWS;
    const float* src = ((row < NROWS) ? X : Y) + (size_t)r * DDIM + kb * 8;
    unsigned short* dh = (row < NROWS) ? Xh : Yh;
    unsigned short* dl = (row < NROWS) ? Xl : Yl;
    float* sq = (row < NROWS) ? x_sq : y_sq;

    float4 a = *(const float4*)src;
    float4 b = *(const float4*)(src + 4);
    float v[8] = {a.x, a.y, a.z, a.w, b.x, b.y, b.z, b.w};
    short8 vh, vl;
    float s = 0.f;
#pragma unroll
    for (int j = 0; j < 8; ++j) {
        s = fmaf(v[j], v[j], s);
        unsigned short h = f2bf(v[j]);
        vh[j] = (short)h;
        vl[j] = (short)f2bf(v[j] - bf2f(h));
    }
    s += __shfl_xor(s, 1);
    s += __shfl_xor(s, 2);
    s += __shfl_xor(s, 4);
    if (kb == 0) sq[r] = s;
    size_t o = ((size_t)(r >> 4) * 8 + kb) * 128 + (size_t)(r & 15) * 8;
    *(short8*)(dh + o) = vh;
    *(short8*)(dl + o) = vl;
}

// One wave's 64x64 Xh*Yh tile (hist use): all 16 fragment loads upfront.
template <typename F>
__device__ inline void compute_tile_hh(const unsigned short* __restrict__ Xh,
                                       const unsigned short* __restrict__ Yh,
                                       int i0, int j0, size_t la, F&& body) {
    const int pa0 = i0 >> 4, pb0 = j0 >> 4;
    short8 fxh[8], fyh[8];
#pragma unroll
    for (int kh = 0; kh < 2; ++kh)
#pragma unroll
        for (int g = 0; g < 4; ++g) {
            fxh[kh * 4 + g] = *(const short8*)(Xh + ((size_t)(pa0 + g) * 8 + kh * 4) * 128 + la);
            fyh[kh * 4 + g] = *(const short8*)(Yh + ((size_t)(pb0 + g) * 8 + kh * 4) * 128 + la);
        }
    f32x4 acc[4][4];
#pragma unroll
    for (int r = 0; r < 4; ++r)
#pragma unroll
        for (int c = 0; c < 4; ++c) acc[r][c] = (f32x4){0.f, 0.f, 0.f, 0.f};
#pragma unroll
    for (int kh = 0; kh < 2; ++kh)
#pragma unroll
        for (int r = 0; r < 4; ++r)
#pragma unroll
            for (int c = 0; c < 4; ++c)
                acc[r][c] = __builtin_amdgcn_mfma_f32_16x16x32_bf16(fxh[kh * 4 + r], fyh[kh * 4 + c], acc[r][c], 0, 0, 0);
    body(acc);
}

// Histogram pass: 128 blocks (4x32); each block does ONE 128x128 tile with a
// rotating column offset so every row and column is sampled 512x (1/8 of the
// matrix, 2.1M samples). Xh*Yh only. LDS-binned, then flushed into one of 8
// sharded global histograms (16-way block contention — cheap).
__launch_bounds__(256, 2)
__global__ void hist_kernel(const unsigned short* __restrict__ Xh,
                            const unsigned short* __restrict__ Yh,
                            const float* __restrict__ x_sq, const float* __restrict__ y_sq,
                            unsigned* __restrict__ hist8) {
    __shared__ unsigned lhist[NBINS];
    const int t    = threadIdx.x;
    const int wave = t >> 6;
    const int lane = t & 63;
    const int fr = lane & 15;
    const int rb = (lane >> 4) * 4;
    const size_t la = (size_t)lane * 8;
    const int i0 = blockIdx.y * 128 + (wave >> 1) * 64;
    const int j0 = blockIdx.x * 1024 + (blockIdx.y & 7) * 128 + (wave & 1) * 64;

#pragma unroll
    for (int i = 0; i < NBINS / 256; ++i) lhist[t + i * 256] = 0u;
    __syncthreads();

    float xsv[4][4];
#pragma unroll
    for (int r = 0; r < 4; ++r)
#pragma unroll
        for (int q = 0; q < 4; ++q) xsv[r][q] = x_sq[i0 + r * 16 + rb + q];
    float ysv[4];
#pragma unroll
    for (int c = 0; c < 4; ++c) ysv[c] = y_sq[j0 + c * 16 + fr];

    compute_tile_hh(Xh, Yh, i0, j0, la, [&](f32x4 (&acc)[4][4]) {
#pragma unroll
        for (int r = 0; r < 4; ++r)
#pragma unroll
            for (int q = 0; q < 4; ++q) {
                float xs = xsv[r][q];
#pragma unroll
                for (int c = 0; c < 4; ++c) {
                    float dv = fmaf(-2.f, acc[r][c][q], xs + ysv[c]);
                    int idx = (int)(dv * HIST_INVW);
                    idx = idx < 0 ? 0 : (idx > NBINS - 1 ? NBINS - 1 : idx);
                    atomicAdd(&lhist[idx], 1u);
                }
            }
    });
    __syncthreads();
    unsigned* dst = hist8 + (size_t)((blockIdx.y * gridDim.x + blockIdx.x) & (NSHARD - 1)) * NBINS;
#pragma unroll
    for (int i = 0; i < NBINS / 256; ++i) {
        unsigned cv = lhist[t + i * 256];
        if (cv) atomicAdd(&dst[t + i * 256], cv);
    }
}

// Exp-write pass, 16x256 wave tiles: grid (16,32); block covers 128 rows x
// 256 cols as 2 row-tiles. Each wave owns 16 rows x 256 cols -> epilogue
// stores are 1KB-CONTIGUOUS per instruction (16 rows x one full 1KB row
// segment), 4x the run length of the old 64x64 tile. Local median recompute
// per block (plain L2-hot loads of prior-kernel shards, no signaling).
__launch_bounds__(256, 2)
__global__ void write_kernel(const unsigned short* __restrict__ Xh, const unsigned short* __restrict__ Xl,
                             const unsigned short* __restrict__ Yh, const unsigned short* __restrict__ Yl,
                             const float* __restrict__ x_sq, const float* __restrict__ y_sq,
                             const unsigned* __restrict__ hist8, float* __restrict__ out) {
    __shared__ float T[4][16][260];   // 66,560 B; per-wave 16x256 tile (scan aliases it)
    __shared__ float s_cc;
    const int t    = threadIdx.x;
    const int wave = t >> 6;
    const int lane = t & 63;
    const int fr = lane & 15;
    const int rb = (lane >> 4) * 4;
    const size_t la = (size_t)lane * 8;
    const int i0 = blockIdx.y * 128;      // block rows
    const int j0 = blockIdx.x * 256;      // block cols
    const int pb0 = j0 >> 4;

    {   // ---- local median: sum 8 shards (plain, coalesced, L2-broadcast),
        // scan in LDS (aliases T), derive cc. All blocks in parallel.
        unsigned* cnt  = (unsigned*)&T[0][0][0];   // 2048 u32
        unsigned* tsum = cnt + NBINS;              // 256 u32
        float*    vmed = (float*)(tsum + 256);     // 2 f32
        unsigned s = 0;
#pragma unroll
        for (int i = 0; i < NBINS / 256; ++i) {
            unsigned b = t * (NBINS / 256) + i;
            unsigned cv = 0;
#pragma unroll
            for (int sd = 0; sd < NSHARD; ++sd)
                cv += hist8[sd * NBINS + b];       // prior-kernel data: plain loads
            cnt[b] = cv;
            s += cv;
        }
        tsum[t] = s;
        __syncthreads();
        for (int off = 1; off < 256; off <<= 1) {
            unsigned v = (t >= off) ? tsum[t - off] : 0u;
            __syncthreads();
            tsum[t] += v;
            __syncthreads();
        }
        unsigned cum = (t == 0) ? 0u : tsum[t - 1];
        unsigned total = tsum[255];
        const unsigned K2 = total >> 1;            // torch median ranks
        const unsigned K1 = K2 - 1u + (total & 1u);
        for (int i = 0; i < NBINS / 256; ++i) {
            int b = t * (NBINS / 256) + i;
            unsigned cv = cnt[b];
            if (cv) {
                if (K1 >= cum && (K1 - cum) < cv)
                    vmed[0] = ((float)b + ((float)(K1 - cum) + 0.5f) / (float)cv) * HIST_W;
                if (K2 >= cum && (K2 - cum) < cv)
                    vmed[1] = ((float)b + ((float)(K2 - cum) + 0.5f) / (float)cv) * HIST_W;
            }
            cum += cv;
        }
        __syncthreads();
        if (t == 0) {
            double med   = 0.5 * ((double)vmed[0] + (double)vmed[1]);
            double gamma = 8.317766166719343 / med;               // ln(4096)/med
            s_cc = (float)(-gamma * 1.4426950408889634);          // -gamma*log2(e)
        }
        __syncthreads();   // s_cc ready; T free for tile reuse
    }
    const float cc = s_cc;

#pragma unroll 1
    for (int rt = 0; rt < 2; ++rt) {
        const int r0 = i0 + rt * 64 + wave * 16;   // wave's 16 rows
        const int pa = r0 >> 4;                    // single X panel

        short8 fxh[2], fxl[2];
#pragma unroll
        for (int kh = 0; kh < 2; ++kh) {
            const size_t ao = ((size_t)pa * 8 + kh * 4) * 128 + la;
            fxh[kh] = *(const short8*)(Xh + ao);
            fxl[kh] = *(const short8*)(Xl + ao);
        }
        float xsq4[4];
#pragma unroll
        for (int q = 0; q < 4; ++q) xsq4[q] = x_sq[r0 + rb + q];

        f32x4 acc[16];
#pragma unroll
        for (int c = 0; c < 16; ++c) acc[c] = (f32x4){0.f, 0.f, 0.f, 0.f};

#pragma unroll 1
        for (int kh = 0; kh < 2; ++kh) {
#pragma unroll 1
            for (int cg = 0; cg < 2; ++cg) {       // 8 Y-panels per register chunk
                short8 gyh[8], gyl[8];
#pragma unroll
                for (int g = 0; g < 8; ++g) {
                    const size_t bo = ((size_t)(pb0 + cg * 8 + g) * 8 + kh * 4) * 128 + la;
                    gyh[g] = *(const short8*)(Yh + bo);
                    gyl[g] = *(const short8*)(Yl + bo);
                }
#pragma unroll
                for (int g = 0; g < 8; ++g) {
                    const int c = cg * 8 + g;
                    acc[c] = __builtin_amdgcn_mfma_f32_16x16x32_bf16(fxh[kh], gyh[g], acc[c], 0, 0, 0);
                    acc[c] = __builtin_amdgcn_mfma_f32_16x16x32_bf16(fxl[kh], gyh[g], acc[c], 0, 0, 0);
                    acc[c] = __builtin_amdgcn_mfma_f32_16x16x32_bf16(fxh[kh], gyl[g], acc[c], 0, 0, 0);
                    acc[c] = __builtin_amdgcn_mfma_f32_16x16x32_bf16(fxl[kh], gyl[g], acc[c], 0, 0, 0);
                }
            }
        }

        // epilogue scatter: T[row_local rb+q][col_local c*16+fr]; 2-way bank
        // aliasing only (row stride 260 -> +4 banks/row; hi +16 banks).
        float* Tw = &T[wave][0][0];
#pragma unroll
        for (int c = 0; c < 16; ++c) {
            float ys = y_sq[j0 + c * 16 + fr];
#pragma unroll
            for (int q = 0; q < 4; ++q) {
                float dv = fmaf(-2.f, acc[c][q], xsq4[q] + ys);
                Tw[(rb + q) * 260 + c * 16 + fr] = __builtin_amdgcn_exp2f(cc * dv);
            }
        }
        // readback + store: 16 rows, each ONE wave-store of 1KB contiguous
        // (64 lanes x 16B) -> 8 full 128B lines per instruction, 4x run length.
#pragma unroll
        for (int ii = 0; ii < 16; ++ii) {
            f32x4 v = *(const f32x4*)&Tw[ii * 260 + lane * 4];
            f32x4* po = (f32x4*)(out + (size_t)(r0 + ii) * NROWS + j0 + lane * 4);
            __builtin_nontemporal_store(v, po);
        }
    }
}

extern "C" void kernel_launch(void* const* d_in, const int* in_sizes, int n_in,
                              void* d_out, int out_size, void* d_ws, size_t ws_size,
                              hipStream_t stream) {
    const float* X = (const float*)d_in[0];
    const float* Y = (const float*)d_in[1];
    float* out = (float*)d_out;

    unsigned* hist8    = (unsigned*)d_ws;
    float* x_sq        = (float*)((char*)d_ws + 65536);
    float* y_sq        = (float*)((char*)d_ws + 81920);
    unsigned short* Xh = (unsigned short*)((char*)d_ws + 131072);
    unsigned short* Xl = Xh + (size_t)NROWS * DDIM;
    unsigned short* Yh = Xl + (size_t)NROWS * DDIM;
    unsigned short* Yl = Yh + (size_t)NROWS * DDIM;

    prep_kernel<<<256, 256, 0, stream>>>(X, Y, Xh, Xl, Yh, Yl, x_sq, y_sq, hist8);
    hist_kernel<<<dim3(4, 32), 256, 0, stream>>>(Xh, Yh, x_sq, y_sq, hist8);
    write_kernel<<<dim3(16, 32), 256, 0, stream>>>(Xh, Xl, Yh, Yl, x_sq, y_sq, hist8, out);
}

// Round 21
// 42.600 us; speedup vs baseline: 1.8256x; 1.8256x over previous
//
#include <hip/hip_runtime.h>
#include <math.h>

#define NROWS 4096
#define DDIM  64
#define NBINS 2048
#define NSHARD 8
#define HIST_W    0.25f    // 2048 bins over [0, 512)
#define HIST_INVW 4.0f

// ws layout (bytes):
// [0      .. 65536  )  hist8[8][2048] u32        -- zeroed by prep each call
// [65536  .. 81920  )  x_sq (4096 f32)
// [81920  .. 98304  )  y_sq (4096 f32)
// [131072 .. 2228224)  Xh, Xl, Yh, Yl (each 4096x64 bf16 = 512 KB)
//
// Fragment-major bf16 layout: (row,k) -> ((row>>4)*8 + (k>>3))*128 + (row&15)*8 + (k&7)
// => one MFMA fragment (16 rows x 32 k) = base + lane*8 shorts (coalesced 1 KB wave load).
//
// HW lessons carried:
//  - R4/R10: wave stores must cover full 128B lines; partial lines amplify ~2x.
//  - R12: prior-launch data is coherent across the kernel boundary -> plain loads.
//  - R14/R15/R16: stores need parallelism AND pipelining (2 blocks/CU x 2 tiles).
//  - R17/R18/R19: nulls on vmcnt order, NT-vs-plain, signaling.
//  - R20: 16x256 wave tile CONFOUNDED the run-length test (4x Y-load
//    redundancy, FETCH 4.8->32MB, issue-bound). This round: same per-wave
//    64x64 work as R19, but the 4 waves tile side-by-side into ONE shared
//    T[64][260]; cross-wave readback gives 1KB-contiguous store runs.

typedef __attribute__((ext_vector_type(8))) short short8;
typedef __attribute__((ext_vector_type(4))) float f32x4;

__device__ inline unsigned short f2bf(float f) {           // RNE f32 -> bf16 bits
    unsigned u = __builtin_bit_cast(unsigned, f);
    u += 0x7FFFu + ((u >> 16) & 1u);
    return (unsigned short)(u >> 16);
}
__device__ inline float bf2f(unsigned short h) {
    unsigned u = ((unsigned)h) << 16;
    return __builtin_bit_cast(float, u);
}

__global__ void prep_kernel(const float* __restrict__ X, const float* __restrict__ Y,
                            unsigned short* __restrict__ Xh, unsigned short* __restrict__ Xl,
                            unsigned short* __restrict__ Yh, unsigned short* __restrict__ Yl,
                            float* __restrict__ x_sq, float* __restrict__ y_sq,
                            unsigned* __restrict__ hist8) {
    int gid = blockIdx.x * blockDim.x + threadIdx.x;       // 0..65535
    if (gid < NSHARD * NBINS) hist8[gid] = 0u;
    int row = gid >> 3, kb = gid & 7;                      // one row-octet per thread
    int r = (row < NROWS) ? row : row - NROWS;
    const float* src = ((row < NROWS) ? X : Y) + (size_t)r * DDIM + kb * 8;
    unsigned short* dh = (row < NROWS) ? Xh : Yh;
    unsigned short* dl = (row < NROWS) ? Xl : Yl;
    float* sq = (row < NROWS) ? x_sq : y_sq;

    float4 a = *(const float4*)src;
    float4 b = *(const float4*)(src + 4);
    float v[8] = {a.x, a.y, a.z, a.w, b.x, b.y, b.z, b.w};
    short8 vh, vl;
    float s = 0.f;
#pragma unroll
    for (int j = 0; j < 8; ++j) {
        s = fmaf(v[j], v[j], s);
        unsigned short h = f2bf(v[j]);
        vh[j] = (short)h;
        vl[j] = (short)f2bf(v[j] - bf2f(h));
    }
    s += __shfl_xor(s, 1);
    s += __shfl_xor(s, 2);
    s += __shfl_xor(s, 4);
    if (kb == 0) sq[r] = s;
    size_t o = ((size_t)(r >> 4) * 8 + kb) * 128 + (size_t)(r & 15) * 8;
    *(short8*)(dh + o) = vh;
    *(short8*)(dl + o) = vl;
}

// One wave's 64x64 Xh*Yh tile (hist use): all 16 fragment loads upfront.
template <typename F>
__device__ inline void compute_tile_hh(const unsigned short* __restrict__ Xh,
                                       const unsigned short* __restrict__ Yh,
                                       int i0, int j0, size_t la, F&& body) {
    const int pa0 = i0 >> 4, pb0 = j0 >> 4;
    short8 fxh[8], fyh[8];
#pragma unroll
    for (int kh = 0; kh < 2; ++kh)
#pragma unroll
        for (int g = 0; g < 4; ++g) {
            fxh[kh * 4 + g] = *(const short8*)(Xh + ((size_t)(pa0 + g) * 8 + kh * 4) * 128 + la);
            fyh[kh * 4 + g] = *(const short8*)(Yh + ((size_t)(pb0 + g) * 8 + kh * 4) * 128 + la);
        }
    f32x4 acc[4][4];
#pragma unroll
    for (int r = 0; r < 4; ++r)
#pragma unroll
        for (int c = 0; c < 4; ++c) acc[r][c] = (f32x4){0.f, 0.f, 0.f, 0.f};
#pragma unroll
    for (int kh = 0; kh < 2; ++kh)
#pragma unroll
        for (int r = 0; r < 4; ++r)
#pragma unroll
            for (int c = 0; c < 4; ++c)
                acc[r][c] = __builtin_amdgcn_mfma_f32_16x16x32_bf16(fxh[kh * 4 + r], fyh[kh * 4 + c], acc[r][c], 0, 0, 0);
    body(acc);
}

// Histogram pass: 128 blocks (4x32); each block does ONE 128x128 tile with a
// rotating column offset so every row and column is sampled 512x (1/8 of the
// matrix, 2.1M samples). Xh*Yh only. LDS-binned, then flushed into one of 8
// sharded global histograms (16-way block contention — cheap).
__launch_bounds__(256, 2)
__global__ void hist_kernel(const unsigned short* __restrict__ Xh,
                            const unsigned short* __restrict__ Yh,
                            const float* __restrict__ x_sq, const float* __restrict__ y_sq,
                            unsigned* __restrict__ hist8) {
    __shared__ unsigned lhist[NBINS];
    const int t    = threadIdx.x;
    const int wave = t >> 6;
    const int lane = t & 63;
    const int fr = lane & 15;
    const int rb = (lane >> 4) * 4;
    const size_t la = (size_t)lane * 8;
    const int i0 = blockIdx.y * 128 + (wave >> 1) * 64;
    const int j0 = blockIdx.x * 1024 + (blockIdx.y & 7) * 128 + (wave & 1) * 64;

#pragma unroll
    for (int i = 0; i < NBINS / 256; ++i) lhist[t + i * 256] = 0u;
    __syncthreads();

    float xsv[4][4];
#pragma unroll
    for (int r = 0; r < 4; ++r)
#pragma unroll
        for (int q = 0; q < 4; ++q) xsv[r][q] = x_sq[i0 + r * 16 + rb + q];
    float ysv[4];
#pragma unroll
    for (int c = 0; c < 4; ++c) ysv[c] = y_sq[j0 + c * 16 + fr];

    compute_tile_hh(Xh, Yh, i0, j0, la, [&](f32x4 (&acc)[4][4]) {
#pragma unroll
        for (int r = 0; r < 4; ++r)
#pragma unroll
            for (int q = 0; q < 4; ++q) {
                float xs = xsv[r][q];
#pragma unroll
                for (int c = 0; c < 4; ++c) {
                    float dv = fmaf(-2.f, acc[r][c][q], xs + ysv[c]);
                    int idx = (int)(dv * HIST_INVW);
                    idx = idx < 0 ? 0 : (idx > NBINS - 1 ? NBINS - 1 : idx);
                    atomicAdd(&lhist[idx], 1u);
                }
            }
    });
    __syncthreads();
    unsigned* dst = hist8 + (size_t)((blockIdx.y * gridDim.x + blockIdx.x) & (NSHARD - 1)) * NBINS;
#pragma unroll
    for (int i = 0; i < NBINS / 256; ++i) {
        unsigned cv = lhist[t + i * 256];
        if (cv) atomicAdd(&dst[t + i * 256], cv);
    }
}

// Exp-write pass: grid (16,32); block = 128 rows x 256 cols as 2 row-steps.
// Per step, the 4 waves compute side-by-side 64x64 tiles (wave w at col
// 64w) into ONE shared T[64][260]; after a barrier, wave w reads back rows
// [16w,16w+16) across all 256 cols and stores 1KB-CONTIGUOUS runs (8 full
// 128B lines per instruction — 4x R19's run length). Per-wave load/MFMA
// work identical to R19. Local median recompute per block (no signaling).
__launch_bounds__(256, 2)
__global__ void write_kernel(const unsigned short* __restrict__ Xh, const unsigned short* __restrict__ Xl,
                             const unsigned short* __restrict__ Yh, const unsigned short* __restrict__ Yl,
                             const float* __restrict__ x_sq, const float* __restrict__ y_sq,
                             const unsigned* __restrict__ hist8, float* __restrict__ out) {
    __shared__ float T[64][260];     // 66,560 B shared tile (scan aliases it)
    __shared__ float s_cc;
    const int t    = threadIdx.x;
    const int wave = t >> 6;
    const int lane = t & 63;
    const int fr = lane & 15;
    const int rb = (lane >> 4) * 4;
    const size_t la = (size_t)lane * 8;
    const int i0 = blockIdx.y * 128;               // block rows
    const int j0 = blockIdx.x * 256;               // block cols
    const int jw = j0 + wave * 64;                 // wave's col strip

    {   // ---- local median: sum 8 shards (plain, coalesced, L2-broadcast),
        // scan in LDS (aliases T), derive cc. All blocks in parallel.
        unsigned* cnt  = (unsigned*)&T[0][0];      // 2048 u32
        unsigned* tsum = cnt + NBINS;              // 256 u32
        float*    vmed = (float*)(tsum + 256);     // 2 f32
        unsigned s = 0;
#pragma unroll
        for (int i = 0; i < NBINS / 256; ++i) {
            unsigned b = t * (NBINS / 256) + i;
            unsigned cv = 0;
#pragma unroll
            for (int sd = 0; sd < NSHARD; ++sd)
                cv += hist8[sd * NBINS + b];       // prior-kernel data: plain loads
            cnt[b] = cv;
            s += cv;
        }
        tsum[t] = s;
        __syncthreads();
        for (int off = 1; off < 256; off <<= 1) {
            unsigned v = (t >= off) ? tsum[t - off] : 0u;
            __syncthreads();
            tsum[t] += v;
            __syncthreads();
        }
        unsigned cum = (t == 0) ? 0u : tsum[t - 1];
        unsigned total = tsum[255];
        const unsigned K2 = total >> 1;            // torch median ranks
        const unsigned K1 = K2 - 1u + (total & 1u);
        for (int i = 0; i < NBINS / 256; ++i) {
            int b = t * (NBINS / 256) + i;
            unsigned cv = cnt[b];
            if (cv) {
                if (K1 >= cum && (K1 - cum) < cv)
                    vmed[0] = ((float)b + ((float)(K1 - cum) + 0.5f) / (float)cv) * HIST_W;
                if (K2 >= cum && (K2 - cum) < cv)
                    vmed[1] = ((float)b + ((float)(K2 - cum) + 0.5f) / (float)cv) * HIST_W;
            }
            cum += cv;
        }
        __syncthreads();
        if (t == 0) {
            double med   = 0.5 * ((double)vmed[0] + (double)vmed[1]);
            double gamma = 8.317766166719343 / med;               // ln(4096)/med
            s_cc = (float)(-gamma * 1.4426950408889634);          // -gamma*log2(e)
        }
        __syncthreads();   // s_cc ready; T free for tile reuse
    }
    const float cc = s_cc;

    // Y fragments: wave's cols fixed across both row-steps -> load ONCE.
    const int pbw = jw >> 4;
    short8 fyh[8], fyl[8];
#pragma unroll
    for (int kh = 0; kh < 2; ++kh)
#pragma unroll
        for (int g = 0; g < 4; ++g) {
            const size_t bo = ((size_t)(pbw + g) * 8 + kh * 4) * 128 + la;
            fyh[kh * 4 + g] = *(const short8*)(Yh + bo);
            fyl[kh * 4 + g] = *(const short8*)(Yl + bo);
        }
    float ysv[4];
#pragma unroll
    for (int c = 0; c < 4; ++c) ysv[c] = y_sq[jw + c * 16 + fr];

#pragma unroll 1
    for (int rt = 0; rt < 2; ++rt) {
        const int r0 = i0 + rt * 64;
        const int pa0 = r0 >> 4;

        short8 fxh[8], fxl[8];
#pragma unroll
        for (int kh = 0; kh < 2; ++kh)
#pragma unroll
            for (int g = 0; g < 4; ++g) {
                const size_t ao = ((size_t)(pa0 + g) * 8 + kh * 4) * 128 + la;
                fxh[kh * 4 + g] = *(const short8*)(Xh + ao);
                fxl[kh * 4 + g] = *(const short8*)(Xl + ao);
            }
        float xsv[4][4];
#pragma unroll
        for (int r = 0; r < 4; ++r)
#pragma unroll
            for (int q = 0; q < 4; ++q) xsv[r][q] = x_sq[r0 + r * 16 + rb + q];

        f32x4 acc[4][4];
#pragma unroll
        for (int r = 0; r < 4; ++r)
#pragma unroll
            for (int c = 0; c < 4; ++c) acc[r][c] = (f32x4){0.f, 0.f, 0.f, 0.f};
#pragma unroll
        for (int kh = 0; kh < 2; ++kh)
#pragma unroll
            for (int r = 0; r < 4; ++r)
#pragma unroll
                for (int c = 0; c < 4; ++c) {
                    acc[r][c] = __builtin_amdgcn_mfma_f32_16x16x32_bf16(fxh[kh * 4 + r], fyh[kh * 4 + c], acc[r][c], 0, 0, 0);
                    acc[r][c] = __builtin_amdgcn_mfma_f32_16x16x32_bf16(fxl[kh * 4 + r], fyh[kh * 4 + c], acc[r][c], 0, 0, 0);
                    acc[r][c] = __builtin_amdgcn_mfma_f32_16x16x32_bf16(fxh[kh * 4 + r], fyl[kh * 4 + c], acc[r][c], 0, 0, 0);
                    acc[r][c] = __builtin_amdgcn_mfma_f32_16x16x32_bf16(fxl[kh * 4 + r], fyl[kh * 4 + c], acc[r][c], 0, 0, 0);
                }

        // scatter: wave w fills cols [64w, 64w+64) of the shared 64-row tile.
        // Per instruction: 4 rb-groups at +1040 words (banks +16 mod 32) ->
        // 2-way aliasing only (free).
#pragma unroll
        for (int r = 0; r < 4; ++r)
#pragma unroll
            for (int c = 0; c < 4; ++c)
#pragma unroll
                for (int q = 0; q < 4; ++q) {
                    float dv = fmaf(-2.f, acc[r][c][q], xsv[r][q] + ysv[c]);
                    T[r * 16 + rb + q][wave * 64 + c * 16 + fr] = __builtin_amdgcn_exp2f(cc * dv);
                }
        __syncthreads();   // all 4 waves' columns in place

        // readback: wave w stores rows [16w,16w+16) as 1KB-contiguous runs
        // (64 lanes x 16B = 8 full 128B lines per instruction).
#pragma unroll
        for (int ii = 0; ii < 16; ++ii) {
            const int row = wave * 16 + ii;
            f32x4 v = *(const f32x4*)&T[row][lane * 4];
            f32x4* po = (f32x4*)(out + (size_t)(r0 + row) * NROWS + j0 + lane * 4);
            __builtin_nontemporal_store(v, po);
        }
        __syncthreads();   // readback done before next step's scatter
    }
}

extern "C" void kernel_launch(void* const* d_in, const int* in_sizes, int n_in,
                              void* d_out, int out_size, void* d_ws, size_t ws_size,
                              hipStream_t stream) {
    const float* X = (const float*)d_in[0];
    const float* Y = (const float*)d_in[1];
    float* out = (float*)d_out;

    unsigned* hist8    = (unsigned*)d_ws;
    float* x_sq        = (float*)((char*)d_ws + 65536);
    float* y_sq        = (float*)((char*)d_ws + 81920);
    unsigned short* Xh = (unsigned short*)((char*)d_ws + 131072);
    unsigned short* Xl = Xh + (size_t)NROWS * DDIM;
    unsigned short* Yh = Xl + (size_t)NROWS * DDIM;
    unsigned short* Yl = Yh + (size_t)NROWS * DDIM;

    prep_kernel<<<256, 256, 0, stream>>>(X, Y, Xh, Xl, Yh, Yl, x_sq, y_sq, hist8);
    hist_kernel<<<dim3(4, 32), 256, 0, stream>>>(Xh, Yh, x_sq, y_sq, hist8);
    write_kernel<<<dim3(16, 32), 256, 0, stream>>>(Xh, Xl, Yh, Yl, x_sq, y_sq, hist8, out);
}